// Round 17
// baseline (204.817 us; speedup 1.0000x reference)
//
#include <hip/hip_runtime.h>
#include <hip/hip_bf16.h>
#include <cstddef>
#include <cstdint>

// Problem sizes (fixed)
#define B_ 16
#define H_ 512
#define N_ 2048
#define DN_ 256
#define G_ 64

typedef __attribute__((ext_vector_type(8))) short short8;
typedef __attribute__((ext_vector_type(4))) short s16x4;
typedef __attribute__((ext_vector_type(4))) float f32x4;

__device__ __forceinline__ unsigned short f2bf(float x) {
    __hip_bfloat16 b = __float2bfloat16(x);
    return *(unsigned short*)&b;
}

__device__ __forceinline__ float bf2f(unsigned short u) {
    return __uint_as_float(((unsigned int)u) << 16);
}

__device__ __forceinline__ short8 pack8(f32x4 a, f32x4 b) {
    short8 r;
    r[0] = (short)f2bf(a[0]); r[1] = (short)f2bf(a[1]);
    r[2] = (short)f2bf(a[2]); r[3] = (short)f2bf(a[3]);
    r[4] = (short)f2bf(b[0]); r[5] = (short)f2bf(b[1]);
    r[6] = (short)f2bf(b[2]); r[7] = (short)f2bf(b[3]);
    return r;
}

// async global->LDS, 16B per lane. LDS dest = wave-uniform base + lane*16.
__device__ __forceinline__ void gl_lds16(const void* g, void* l) {
    __builtin_amdgcn_global_load_lds(
        (const __attribute__((address_space(1))) unsigned int*)g,
        (__attribute__((address_space(3))) unsigned int*)l, 16, 0, 0);
}

// manual grid barrier: all 256 blocks are co-resident (1 block/CU by LDS),
// counters zeroed by hipMemsetAsync before each launch.
__device__ __forceinline__ void grid_barrier(unsigned int* ctr) {
    __syncthreads();
    __threadfence();   // release: make this block's writes device-visible
    if (threadIdx.x == 0) {
        __hip_atomic_fetch_add(ctr, 1u, __ATOMIC_RELEASE, __HIP_MEMORY_SCOPE_AGENT);
        while (__hip_atomic_load(ctr, __ATOMIC_ACQUIRE, __HIP_MEMORY_SCOPE_AGENT) < 256u) {
            __builtin_amdgcn_s_sleep(1);
        }
    }
    __syncthreads();
    __threadfence();   // acquire: invalidate caches before reading others' data
}

// ---------------- workspace layout (bytes) ----------------
static constexpr size_t OFF_Q      = 0;                          // 16*64 f32
static constexpr size_t OFF_KT     = 4096;                       // kTb[64][2048] bf16
static constexpr size_t OFF_V      = OFF_KT + (size_t)N_*G_*4;   // 2048*64 f32
static constexpr size_t OFF_ALPHA  = OFF_V + (size_t)N_*G_*4;    // 16*2048 f32
static constexpr size_t OFF_DIS    = OFF_ALPHA + (size_t)B_*N_*4;
static constexpr size_t OFF_ROWSUM = OFF_DIS + (size_t)B_*N_*4;  // 2048 f32
static constexpr size_t OFF_ABF    = OFF_ROWSUM + 8192;          // 2048*2048 bf16
static constexpr size_t OFF_VPT    = OFF_ABF + (size_t)N_*N_*2;  // 1024*2048 bf16
static constexpr size_t OFF_BAR    = OFF_VPT + (size_t)(B_*G_)*N_*2; // barrier ctrs

#define BM 64
#define BN 64
#define BK 128
#define NKT (N_ / BK)   // 16 K-tiles

// ---------------- single kernel (256 blocks): prep | attn | gemm+epilogue --------
__global__ __launch_bounds__(256) void mega_kernel(
    const float* __restrict__ h_t, const float* __restrict__ Wq, const float* __restrict__ bq,
    const float* __restrict__ node_repr, const float* __restrict__ Wk, const float* __restrict__ bk,
    const float* __restrict__ Wv, const float* __restrict__ bv, const float* __restrict__ base_adj,
    float* __restrict__ q, __hip_bfloat16* __restrict__ kTb, float* __restrict__ v,
    __hip_bfloat16* __restrict__ Abf, float* __restrict__ rowsum,
    __hip_bfloat16* __restrict__ VpT, float* __restrict__ alpha, float* __restrict__ dis,
    const float* __restrict__ Wo, const float* __restrict__ bo,
    const float* __restrict__ gamma, const float* __restrict__ beta,
    float* __restrict__ un, float* __restrict__ out, unsigned int* __restrict__ bar) {
    __shared__ __align__(16) char smem[67072];
    const int bid = blockIdx.x, tid = threadIdx.x;
    const int wave = tid >> 6, l = tid & 63;
    const int lr = l & 15, kg = l >> 4;

    // ================= P1: prep =================
    {
        // streaming rowsum + bf16 cast: 8 rows per block (2 per wave)
        {
            int u = (bid >= 17) ? (bid - 17) : (239 + bid);
            #pragma unroll
            for (int rr = 0; rr < 2; rr++) {
                const int n = u * 8 + wave * 2 + rr;
                const f32x4* src = (const f32x4*)(base_adj + (size_t)n * N_);
                s16x4* dst = (s16x4*)(Abf + (size_t)n * N_);
                float s = 0.f;
                #pragma unroll
                for (int i = 0; i < 8; i++) {
                    int m4 = l + i * 64;
                    f32x4 x = src[m4];
                    s += x[0] + x[1] + x[2] + x[3];
                    s16x4 o;
                    o[0] = (short)f2bf(x[0]); o[1] = (short)f2bf(x[1]);
                    o[2] = (short)f2bf(x[2]); o[3] = (short)f2bf(x[3]);
                    dst[m4] = o;
                }
                #pragma unroll
                for (int off = 32; off; off >>= 1) s += __shfl_xor(s, off, 64);
                if (l == 0) rowsum[n] = s;
            }
        }
        if (bid < 16) {
            // ---- k,v projection via MFMA: cols = [k(0..63)|v(64..127)] ----
            short* Xs = (short*)smem;              // [128][64] bf16, col16 ^= row&7
            short* Ws = (short*)(smem + 16384);    // [128][64] bf16
            const int n0 = bid * 128;
            f32x4 acc[2][8];
            #pragma unroll
            for (int fr = 0; fr < 2; fr++)
                #pragma unroll
                for (int fc = 0; fc < 8; fc++) acc[fr][fc] = (f32x4){0.f, 0.f, 0.f, 0.f};
            for (int kt = 0; kt < 4; kt++) {
                __syncthreads();
                #pragma unroll
                for (int j = 0; j < 4; j++) {          // stage X (nodes)
                    int c = tid + j * 256;
                    int row = c >> 3, c16 = c & 7;
                    const float* src = node_repr + (size_t)(n0 + row) * DN_ + kt * 64 + c16 * 8;
                    *(short8*)&Xs[(row * 8 + (c16 ^ (row & 7))) * 8] =
                        pack8(*(const f32x4*)src, *(const f32x4*)(src + 4));
                }
                #pragma unroll
                for (int j = 0; j < 4; j++) {          // stage W = [Wk;Wv]
                    int c = tid + j * 256;
                    int row = c >> 3, c16 = c & 7;
                    const float* src = (row < 64)
                        ? (Wk + (size_t)row * DN_ + kt * 64 + c16 * 8)
                        : (Wv + (size_t)(row - 64) * DN_ + kt * 64 + c16 * 8);
                    *(short8*)&Ws[(row * 8 + (c16 ^ (row & 7))) * 8] =
                        pack8(*(const f32x4*)src, *(const f32x4*)(src + 4));
                }
                __syncthreads();
                #pragma unroll
                for (int ks = 0; ks < 2; ks++) {
                    short8 af[2], bf[8];
                    #pragma unroll
                    for (int fr = 0; fr < 2; fr++) {
                        int row = wave * 32 + fr * 16 + lr;
                        af[fr] = *(const short8*)&Xs[(row * 8 + ((ks * 4 + kg) ^ (row & 7))) * 8];
                    }
                    #pragma unroll
                    for (int fc = 0; fc < 8; fc++) {
                        int row = fc * 16 + lr;
                        bf[fc] = *(const short8*)&Ws[(row * 8 + ((ks * 4 + kg) ^ (row & 7))) * 8];
                    }
                    #pragma unroll
                    for (int fr = 0; fr < 2; fr++)
                        #pragma unroll
                        for (int fc = 0; fc < 8; fc++)
                            acc[fr][fc] = __builtin_amdgcn_mfma_f32_16x16x32_bf16(af[fr], bf[fc], acc[fr][fc], 0, 0, 0);
                }
            }
            #pragma unroll
            for (int fr = 0; fr < 2; fr++) {
                int nb = n0 + wave * 32 + fr * 16 + kg * 4;
                #pragma unroll
                for (int fc = 0; fc < 4; fc++) {       // k half -> kTb[g][n] bf16
                    int cc = fc * 16 + lr;
                    float bias = bk[cc];
                    s16x4 o;
                    o[0] = (short)f2bf(acc[fr][fc][0] + bias);
                    o[1] = (short)f2bf(acc[fr][fc][1] + bias);
                    o[2] = (short)f2bf(acc[fr][fc][2] + bias);
                    o[3] = (short)f2bf(acc[fr][fc][3] + bias);
                    *(s16x4*)&kTb[(size_t)cc * N_ + nb] = o;
                }
                #pragma unroll
                for (int fc = 4; fc < 8; fc++) {       // v half -> v[n][g]
                    int cv = fc * 16 + lr - 64;
                    float bias = bv[cv];
                    #pragma unroll
                    for (int r = 0; r < 4; r++)
                        v[(size_t)(nb + r) * G_ + cv] = acc[fr][fc][r] + bias;
                }
            }
        } else if (bid == 16) {
            // zero both summary accumulators
            #pragma unroll
            for (int j = 0; j < 8; j++) out[tid + j * 256] = 0.f;
            // ---- q projection via MFMA ----
            short* Hs = (short*)smem;              // [16][128] bf16
            short* Wqs = (short*)(smem + 4096);    // [64][128] bf16
            f32x4 acc[4];
            #pragma unroll
            for (int fc = 0; fc < 4; fc++) acc[fc] = (f32x4){0.f, 0.f, 0.f, 0.f};
            for (int kt = 0; kt < 4; kt++) {
                __syncthreads();
                {   // stage h_t
                    int row = tid >> 4, c16 = tid & 15;
                    const float* src = h_t + (size_t)row * H_ + kt * 128 + c16 * 8;
                    *(short8*)&Hs[(row * 16 + (c16 ^ (row & 7))) * 8] =
                        pack8(*(const f32x4*)src, *(const f32x4*)(src + 4));
                }
                #pragma unroll
                for (int j = 0; j < 4; j++) {          // stage Wq
                    int c = tid + j * 256;
                    int row = c >> 4, c16 = c & 15;
                    const float* src = Wq + (size_t)row * H_ + kt * 128 + c16 * 8;
                    *(short8*)&Wqs[(row * 16 + (c16 ^ (row & 7))) * 8] =
                        pack8(*(const f32x4*)src, *(const f32x4*)(src + 4));
                }
                __syncthreads();
                if (wave == 0) {
                    #pragma unroll
                    for (int ks = 0; ks < 4; ks++) {
                        short8 af = *(const short8*)&Hs[(lr * 16 + ((ks * 4 + kg) ^ (lr & 7))) * 8];
                        #pragma unroll
                        for (int fc = 0; fc < 4; fc++) {
                            int row = fc * 16 + lr;
                            short8 bf = *(const short8*)&Wqs[(row * 16 + ((ks * 4 + kg) ^ (row & 7))) * 8];
                            acc[fc] = __builtin_amdgcn_mfma_f32_16x16x32_bf16(af, bf, acc[fc], 0, 0, 0);
                        }
                    }
                }
            }
            if (wave == 0) {
                #pragma unroll
                for (int fc = 0; fc < 4; fc++) {
                    int gcol = fc * 16 + lr;
                    float bias = bq[gcol];
                    #pragma unroll
                    for (int r = 0; r < 4; r++)
                        q[(kg * 4 + r) * G_ + gcol] = acc[fc][r] + bias;
                }
            }
        }
    }
    grid_barrier(&bar[0]);

    // ================= P2: softmax + VpT slice (128 m) + rel partial =============
    {
        const int b2 = bid >> 4, chunk = bid & 15;
        float* qs  = (float*)smem;                 // [64]
        float* red = (float*)(smem + 256);         // [8]
        float* als = (float*)(smem + 512);         // [2048]
        float* dss = (float*)(smem + 8704);        // [2048]
        float* vsb = (float*)(smem + 16896);       // [128][65]
        if (tid < G_) qs[tid] = q[b2 * G_ + tid];
        __syncthreads();
        const unsigned short* kr = (const unsigned short*)kTb;
        float lg[8];
        #pragma unroll
        for (int e = 0; e < 8; e++) lg[e] = 0.f;
        for (int g = 0; g < G_; g++) {
            float qq = qs[g];
            short8 k8 = *(const short8*)&kr[(size_t)g * N_ + tid * 8];
            #pragma unroll
            for (int e = 0; e < 8; e++)
                lg[e] = fmaf(qq, bf2f((unsigned short)k8[e]), lg[e]);
        }
        #pragma unroll
        for (int e = 0; e < 8; e++) lg[e] *= 0.125f;
        float mx = lg[0];
        #pragma unroll
        for (int e = 1; e < 8; e++) mx = fmaxf(mx, lg[e]);
        #pragma unroll
        for (int off = 32; off; off >>= 1) mx = fmaxf(mx, __shfl_xor(mx, off, 64));
        if (l == 0) red[wave] = mx;
        __syncthreads();
        mx = fmaxf(fmaxf(red[0], red[1]), fmaxf(red[2], red[3]));
        float a[8];
        float ssum = 0.f;
        #pragma unroll
        for (int e = 0; e < 8; e++) { a[e] = expf(lg[e] - mx); ssum += a[e]; }
        #pragma unroll
        for (int off = 32; off; off >>= 1) ssum += __shfl_xor(ssum, off, 64);
        if (l == 0) red[4 + wave] = ssum;
        __syncthreads();
        float inv = 1.f / (red[4] + red[5] + red[6] + red[7]);
        f32x4 rs0 = *(const f32x4*)&rowsum[tid * 8];
        f32x4 rs1 = *(const f32x4*)&rowsum[tid * 8 + 4];
        f32x4 av0, av1, dv0, dv1;
        #pragma unroll
        for (int e = 0; e < 4; e++) {
            av0[e] = a[e] * inv;
            dv0[e] = rsqrtf(fmaf(av0[e], rs0[e], 1.f + 1e-8f));
            av1[e] = a[4 + e] * inv;
            dv1[e] = rsqrtf(fmaf(av1[e], rs1[e], 1.f + 1e-8f));
        }
        *(f32x4*)&als[tid * 8] = av0; *(f32x4*)&als[tid * 8 + 4] = av1;
        *(f32x4*)&dss[tid * 8] = dv0; *(f32x4*)&dss[tid * 8 + 4] = dv1;
        if (chunk == 0) {
            *(f32x4*)&alpha[(size_t)b2 * N_ + tid * 8] = av0;
            *(f32x4*)&alpha[(size_t)b2 * N_ + tid * 8 + 4] = av1;
            *(f32x4*)&dis[(size_t)b2 * N_ + tid * 8] = dv0;
            *(f32x4*)&dis[(size_t)b2 * N_ + tid * 8 + 4] = dv1;
        }
        __syncthreads();
        // stage v slice [m0, m0+128)
        const int m0 = chunk * 128;
        {
            int mm = tid >> 1, g4 = (tid & 1) * 32;
            #pragma unroll
            for (int i = 0; i < 8; i++) {
                f32x4 x = *(const f32x4*)&v[(size_t)(m0 + mm) * G_ + g4 + i * 4];
                vsb[mm * 65 + g4 + i * 4 + 0] = x[0];
                vsb[mm * 65 + g4 + i * 4 + 1] = x[1];
                vsb[mm * 65 + g4 + i * 4 + 2] = x[2];
                vsb[mm * 65 + g4 + i * 4 + 3] = x[3];
            }
        }
        __syncthreads();
        const int gg = tid >> 2, mb = (tid & 3) * 4;
        float relacc = 0.f;
        #pragma unroll
        for (int j4 = 0; j4 < 8; j4++) {
            int mloc = mb + j4 * 16;
            s16x4 pk;
            #pragma unroll
            for (int j = 0; j < 4; j++) {
                int mm2 = mloc + j;
                float vv = vsb[mm2 * 65 + gg];
                pk[j] = (short)f2bf(dss[m0 + mm2] * vv);
                relacc = fmaf(als[m0 + mm2], vv, relacc);
            }
            *(s16x4*)&VpT[((size_t)b2 * G_ + gg) * N_ + m0 + mloc] = pk;
        }
        __syncthreads();
        als[tid] = relacc;
        __syncthreads();
        if (tid < G_) {
            float r = als[tid * 4] + als[tid * 4 + 1] + als[tid * 4 + 2] + als[tid * 4 + 3];
            atomicAdd(&out[1024 + b2 * G_ + tid], r);   // relation_vector partial
        }
    }
    grid_barrier(&bar[16]);

    // ================= P3: split-K GEMM + fused epilogue (2 tiles/block) =========
    for (int half = 0; half < 2; half++) {
        float* ad_s = (float*)(smem + 65536);      // [2][64]: alpha, dis
        float* psum_w = (float*)(smem + 66048);    // [4][64]
        const int wg = bid + half * 256;      // 0..511
        const int xcd = wg & 7, c = wg >> 3;  // c in 0..63
        const int n0 = (c >> 1) * BM;         // 32 row panels
        const int b = xcd * 2 + (c & 1);      // batch index
        const int c0 = b * BN;

        __syncthreads();   // LDS free from previous phase/half
        if (tid < BM) {
            ad_s[tid] = alpha[(size_t)b * N_ + n0 + tid];
            ad_s[64 + tid] = dis[(size_t)b * N_ + n0 + tid];
        }

        f32x4 acc[4][4];
        #pragma unroll
        for (int m = 0; m < 4; m++)
            #pragma unroll
            for (int n = 0; n < 4; n++) acc[m][n] = (f32x4){0.f, 0.f, 0.f, 0.f};

        const int srow = tid >> 4;            // 0..15
        const int c16s = tid & 15;
        const int scol = ((c16s & 8) | ((c16s ^ srow) & 7)) << 3;  // element offset
        const __hip_bfloat16* ag = Abf + (size_t)(n0 + srow) * N_ + scol;
        const __hip_bfloat16* bg = VpT + (size_t)(c0 + srow) * N_ + scol;

        #define STAGE(bufidx, kpos)                                               \
            do {                                                                  \
                short* Ad = (short*)(smem + (bufidx) * 16384);                    \
                short* Bd = (short*)(smem + 32768 + (bufidx) * 16384);            \
                _Pragma("unroll")                                                 \
                for (int j = 0; j < 4; j++)                                       \
                    gl_lds16(ag + (size_t)j * 16 * N_ + (kpos),                   \
                             &Ad[(wave * 4 + j * 16) * BK]);                      \
                _Pragma("unroll")                                                 \
                for (int j = 0; j < 4; j++)                                       \
                    gl_lds16(bg + (size_t)j * 16 * N_ + (kpos),                   \
                             &Bd[(wave * 4 + j * 16) * BK]);                      \
            } while (0)

        STAGE(0, 0);
        __syncthreads();

        const int chunk = wave * 4 + kg;                    // this wave's k-chunk
        const int swc = ((chunk & 8) | ((chunk ^ lr) & 7)) * 8;
        int cur = 0;
        for (int t = 0; t < NKT; t++) {
            if (t + 1 < NKT) STAGE(cur ^ 1, (t + 1) * BK);
            const short* Ab = (const short*)(smem + cur * 16384);
            const short* Bb = (const short*)(smem + 32768 + cur * 16384);
            short8 av[4], bv2[4];
            #pragma unroll
            for (int m = 0; m < 4; m++)
                av[m] = *(const short8*)&Ab[(m * 16 + lr) * BK + swc];
            #pragma unroll
            for (int n = 0; n < 4; n++)
                bv2[n] = *(const short8*)&Bb[(n * 16 + lr) * BK + swc];
            #pragma unroll
            for (int m = 0; m < 4; m++)
                #pragma unroll
                for (int n = 0; n < 4; n++)
                    acc[m][n] = __builtin_amdgcn_mfma_f32_16x16x32_bf16(av[m], bv2[n], acc[m][n], 0, 0, 0);
            __syncthreads();
            cur ^= 1;
        }
        #undef STAGE

        // cross-wave k-reduction through LDS
        float* red = (float*)smem;
        #pragma unroll
        for (int m = 0; m < 4; m++)
            #pragma unroll
            for (int n = 0; n < 4; n++)
                *(f32x4*)&red[((wave * 16 + m * 4 + n) * 64 + l) * 4] = acc[m][n];
        __syncthreads();
        f32x4 cfin[4];
        #pragma unroll
        for (int n = 0; n < 4; n++) {
            f32x4 s0 = *(const f32x4*)&red[((0 + wave * 4 + n) * 64 + l) * 4];
            f32x4 s1 = *(const f32x4*)&red[((16 + wave * 4 + n) * 64 + l) * 4];
            f32x4 s2 = *(const f32x4*)&red[((32 + wave * 4 + n) * 64 + l) * 4];
            f32x4 s3 = *(const f32x4*)&red[((48 + wave * 4 + n) * 64 + l) * 4];
            cfin[n] = (s0 + s1) + (s2 + s3);
        }
        __syncthreads();

        unsigned short* z_s = (unsigned short*)smem;
        uint32_t* wo_s = (uint32_t*)(smem + 32768);

        {   // stage Wo (f32 -> packed bf16, swizzle dword col by (g&7)<<2)
            int g = tid >> 2;
            int j0 = (tid & 3) * 16;
            #pragma unroll
            for (int jj = 0; jj < 8; jj++) {
                int g2 = j0 + jj * 2;
                uint32_t pk = (uint32_t)f2bf(Wo[g * G_ + g2]) |
                              ((uint32_t)f2bf(Wo[g * G_ + g2 + 1]) << 16);
                int dwc = ((g2 >> 1) ^ ((g & 7) << 2)) & 31;
                wo_s[g * 32 + dwc] = pk;
            }
        }
        #pragma unroll
        for (int nn = 0; nn < 4; nn++)
            #pragma unroll
            for (int r = 0; r < 4; r++) {
                int row = wave * 16 + kg * 4 + r;
                int g2 = nn * 16 + lr;
                float al = ad_s[row], di = ad_s[64 + row];
                float vv = v[(size_t)(n0 + row) * G_ + g2];
                float zp = di * fmaf(al, cfin[nn][r], di * vv);
                int dwc = ((g2 >> 1) ^ (((row >> 2) & 3) << 3)) & 31;
                z_s[(row * 32 + dwc) * 2 + (g2 & 1)] = f2bf(zp);
            }
        float bo_l[4], ga_l[4], be_l[4];
        #pragma unroll
        for (int ct = 0; ct < 4; ct++) {
            bo_l[ct] = bo[ct * 16 + lr];
            ga_l[ct] = gamma[ct * 16 + lr];
            be_l[ct] = beta[ct * 16 + lr];
        }
        __syncthreads();

        short8 aw[2], bw[4][2];
        #pragma unroll
        for (int kh = 0; kh < 2; kh++) {
            int arow = wave * 16 + lr;
            int dwc = ((kh * 16 + kg * 4) ^ (((arow >> 2) & 3) << 3)) & 31;
            aw[kh] = *(const short8*)&z_s[(arow * 32 + dwc) * 2];
        }
        #pragma unroll
        for (int ct = 0; ct < 4; ct++) {
            int col = ct * 16 + lr;
            #pragma unroll
            for (int kh = 0; kh < 2; kh++) {
                int dwc = ((kh * 16 + kg * 4) ^ ((col & 7) << 2)) & 31;
                bw[ct][kh] = *(const short8*)&((unsigned short*)wo_s)[(col * 32 + dwc) * 2];
            }
        }
        f32x4 acc2[4];
        #pragma unroll
        for (int ct = 0; ct < 4; ct++) acc2[ct] = (f32x4){0.f, 0.f, 0.f, 0.f};
        #pragma unroll
        for (int kh = 0; kh < 2; kh++)
            #pragma unroll
            for (int ct = 0; ct < 4; ct++)
                acc2[ct] = __builtin_amdgcn_mfma_f32_16x16x32_bf16(aw[kh], bw[ct][kh], acc2[ct], 0, 0, 0);

        float psum_l[4] = {0.f, 0.f, 0.f, 0.f};
        #pragma unroll
        for (int rr = 0; rr < 4; rr++) {
            int lrow = wave * 16 + kg * 4 + rr;
            float y[4], s = 0.f;
            #pragma unroll
            for (int ct = 0; ct < 4; ct++) {
                y[ct] = fmaxf(acc2[ct][rr] + bo_l[ct], 0.f);
                s += y[ct];
            }
            s += __shfl_xor(s, 1, 64); s += __shfl_xor(s, 2, 64);
            s += __shfl_xor(s, 4, 64); s += __shfl_xor(s, 8, 64);
            float mu = s * (1.f / 64.f);
            float s2 = 0.f;
            #pragma unroll
            for (int ct = 0; ct < 4; ct++) { float d = y[ct] - mu; s2 += d * d; }
            s2 += __shfl_xor(s2, 1, 64); s2 += __shfl_xor(s2, 2, 64);
            s2 += __shfl_xor(s2, 4, 64); s2 += __shfl_xor(s2, 8, 64);
            float rstd = rsqrtf(s2 * (1.f / 64.f) + 1e-5f);
            float al = ad_s[lrow];
            size_t ubase = ((size_t)b * N_ + n0 + lrow) * G_;
            #pragma unroll
            for (int ct = 0; ct < 4; ct++) {
                float outv = fmaf((y[ct] - mu) * rstd, ga_l[ct], be_l[ct]);
                un[ubase + ct * 16 + lr] = outv;
                psum_l[ct] = fmaf(al, outv, psum_l[ct]);
            }
        }
        #pragma unroll
        for (int ct = 0; ct < 4; ct++) {
            psum_l[ct] += __shfl_xor(psum_l[ct], 16, 64);
            psum_l[ct] += __shfl_xor(psum_l[ct], 32, 64);
        }
        if (kg == 0)
            #pragma unroll
            for (int ct = 0; ct < 4; ct++) psum_w[wave * 64 + ct * 16 + lr] = psum_l[ct];
        __syncthreads();
        if (tid < G_) {
            float p = psum_w[tid] + psum_w[64 + tid] + psum_w[128 + tid] + psum_w[192 + tid];
            atomicAdd(&out[b * G_ + tid], p);     // propagated_summary
        }
    }
}

extern "C" void kernel_launch(void* const* d_in, const int* in_sizes, int n_in,
                              void* d_out, int out_size, void* d_ws, size_t ws_size,
                              hipStream_t stream) {
    const float* h_t       = (const float*)d_in[0];
    const float* node_repr = (const float*)d_in[1];
    const float* base_adj  = (const float*)d_in[2];
    const float* Wq    = (const float*)d_in[3];
    const float* bq    = (const float*)d_in[4];
    const float* Wk    = (const float*)d_in[5];
    const float* bk    = (const float*)d_in[6];
    const float* Wv    = (const float*)d_in[7];
    const float* bv    = (const float*)d_in[8];
    const float* Wo    = (const float*)d_in[9];
    const float* bo    = (const float*)d_in[10];
    const float* gamma = (const float*)d_in[11];
    const float* beta  = (const float*)d_in[12];
    float* out = (float*)d_out;

    char* ws = (char*)d_ws;
    float* q      = (float*)(ws + OFF_Q);
    __hip_bfloat16* kTb = (__hip_bfloat16*)(ws + OFF_KT);
    float* v      = (float*)(ws + OFF_V);
    float* alpha  = (float*)(ws + OFF_ALPHA);
    float* dis    = (float*)(ws + OFF_DIS);
    float* rowsum = (float*)(ws + OFF_ROWSUM);
    __hip_bfloat16* Abf = (__hip_bfloat16*)(ws + OFF_ABF);
    __hip_bfloat16* VpT = (__hip_bfloat16*)(ws + OFF_VPT);
    unsigned int* bar   = (unsigned int*)(ws + OFF_BAR);

    float* un = out + 2048; // updated_nodes region

    hipMemsetAsync(bar, 0, 256, stream);   // zero barrier counters every call
    mega_kernel<<<256, 256, 0, stream>>>(h_t, Wq, bq, node_repr, Wk, bk, Wv, bv,
                                         base_adj, q, kTb, v, Abf, rowsum, VpT,
                                         alpha, dis, Wo, bo, gamma, beta, un, out, bar);
}

// Round 18
// 48.792 us; speedup vs baseline: 4.1978x; 4.1978x over previous
//
#include <hip/hip_runtime.h>
#include <hip/hip_bf16.h>
#include <cstddef>
#include <cstdint>

// Problem sizes (fixed)
#define B_ 16
#define H_ 512
#define N_ 2048
#define DN_ 256
#define G_ 64

typedef __attribute__((ext_vector_type(8))) short short8;
typedef __attribute__((ext_vector_type(4))) short s16x4;
typedef __attribute__((ext_vector_type(4))) float f32x4;

__device__ __forceinline__ unsigned short f2bf(float x) {
    __hip_bfloat16 b = __float2bfloat16(x);
    return *(unsigned short*)&b;
}

__device__ __forceinline__ float bf2f(unsigned short u) {
    return __uint_as_float(((unsigned int)u) << 16);
}

__device__ __forceinline__ short8 pack8(f32x4 a, f32x4 b) {
    short8 r;
    r[0] = (short)f2bf(a[0]); r[1] = (short)f2bf(a[1]);
    r[2] = (short)f2bf(a[2]); r[3] = (short)f2bf(a[3]);
    r[4] = (short)f2bf(b[0]); r[5] = (short)f2bf(b[1]);
    r[6] = (short)f2bf(b[2]); r[7] = (short)f2bf(b[3]);
    return r;
}

// async global->LDS, 16B per lane. LDS dest = wave-uniform base + lane*16.
__device__ __forceinline__ void gl_lds16(const void* g, void* l) {
    __builtin_amdgcn_global_load_lds(
        (const __attribute__((address_space(1))) unsigned int*)g,
        (__attribute__((address_space(3))) unsigned int*)l, 16, 0, 0);
}

// ---------------- workspace layout (bytes) ----------------
static constexpr size_t OFF_Q      = 0;                          // 16*64 f32
static constexpr size_t OFF_KT     = 4096;                       // kTb[64][2048] bf16
static constexpr size_t OFF_V      = OFF_KT + (size_t)N_*G_*4;   // 2048*64 f32
static constexpr size_t OFF_ALPHA  = OFF_V + (size_t)N_*G_*4;    // 16*2048 f32
static constexpr size_t OFF_DIS    = OFF_ALPHA + (size_t)B_*N_*4;
static constexpr size_t OFF_ROWSUM = OFF_DIS + (size_t)B_*N_*4;  // 2048 f32
static constexpr size_t OFF_ABF    = OFF_ROWSUM + 8192;          // 2048*2048 bf16
static constexpr size_t OFF_VPT    = OFF_ABF + (size_t)N_*N_*2;  // 1024*2048 bf16

// ---------------- K1: fused prep: kv-MFMA | q-MFMA+zero | rowsum+cast ----------
// bid 0..15:  kv GEMM, 128 nodes each: C[128 nodes][128 = k|v] = X @ [Wk;Wv]^T
// bid 16:     q GEMM (16x64, K=512) + zero out[0:2048]
// bid 17..528: rowsum_cast, 4 rows per block (1 row per wave, no barriers)
__global__ __launch_bounds__(256) void prep_kernel(const float* __restrict__ h_t,
                                                   const float* __restrict__ Wq,
                                                   const float* __restrict__ bq,
                                                   const float* __restrict__ node_repr,
                                                   const float* __restrict__ Wk,
                                                   const float* __restrict__ bk,
                                                   const float* __restrict__ Wv,
                                                   const float* __restrict__ bv,
                                                   const float* __restrict__ base_adj,
                                                   float* __restrict__ q,
                                                   __hip_bfloat16* __restrict__ kTb,
                                                   float* __restrict__ v,
                                                   __hip_bfloat16* __restrict__ Abf,
                                                   float* __restrict__ rowsum,
                                                   float* __restrict__ out) {
    __shared__ __align__(16) short smem[16384];   // 32 KB
    const int bid = blockIdx.x, tid = threadIdx.x;
    const int wave = tid >> 6, l = tid & 63;
    const int lr = l & 15, kg = l >> 4;
    if (bid < 16) {
        // ---- k,v projection via MFMA: rows = nodes, cols = [k(0..63)|v(64..127)] ----
        short* Xs = smem;           // [128][64] bf16, col16 ^= row&7
        short* Ws = smem + 8192;    // [128][64] bf16
        const int n0 = bid * 128;
        f32x4 acc[2][8];
        #pragma unroll
        for (int fr = 0; fr < 2; fr++)
            #pragma unroll
            for (int fc = 0; fc < 8; fc++) acc[fr][fc] = (f32x4){0.f, 0.f, 0.f, 0.f};
        for (int kt = 0; kt < 4; kt++) {
            __syncthreads();
            #pragma unroll
            for (int j = 0; j < 4; j++) {          // stage X (nodes)
                int c = tid + j * 256;
                int row = c >> 3, c16 = c & 7;
                const float* src = node_repr + (size_t)(n0 + row) * DN_ + kt * 64 + c16 * 8;
                *(short8*)&Xs[(row * 8 + (c16 ^ (row & 7))) * 8] =
                    pack8(*(const f32x4*)src, *(const f32x4*)(src + 4));
            }
            #pragma unroll
            for (int j = 0; j < 4; j++) {          // stage W = [Wk;Wv]
                int c = tid + j * 256;
                int row = c >> 3, c16 = c & 7;
                const float* src = (row < 64)
                    ? (Wk + (size_t)row * DN_ + kt * 64 + c16 * 8)
                    : (Wv + (size_t)(row - 64) * DN_ + kt * 64 + c16 * 8);
                *(short8*)&Ws[(row * 8 + (c16 ^ (row & 7))) * 8] =
                    pack8(*(const f32x4*)src, *(const f32x4*)(src + 4));
            }
            __syncthreads();
            #pragma unroll
            for (int ks = 0; ks < 2; ks++) {
                short8 af[2], bf[8];
                #pragma unroll
                for (int fr = 0; fr < 2; fr++) {
                    int row = wave * 32 + fr * 16 + lr;
                    af[fr] = *(const short8*)&Xs[(row * 8 + ((ks * 4 + kg) ^ (row & 7))) * 8];
                }
                #pragma unroll
                for (int fc = 0; fc < 8; fc++) {
                    int row = fc * 16 + lr;
                    bf[fc] = *(const short8*)&Ws[(row * 8 + ((ks * 4 + kg) ^ (row & 7))) * 8];
                }
                #pragma unroll
                for (int fr = 0; fr < 2; fr++)
                    #pragma unroll
                    for (int fc = 0; fc < 8; fc++)
                        acc[fr][fc] = __builtin_amdgcn_mfma_f32_16x16x32_bf16(af[fr], bf[fc], acc[fr][fc], 0, 0, 0);
            }
        }
        // epilogue: C row (kg*4+r) = node, col (lr) = channel
        #pragma unroll
        for (int fr = 0; fr < 2; fr++) {
            int nb = n0 + wave * 32 + fr * 16 + kg * 4;
            #pragma unroll
            for (int fc = 0; fc < 4; fc++) {       // k half -> kTb[g][n] bf16
                int cc = fc * 16 + lr;
                float bias = bk[cc];
                s16x4 o;
                o[0] = (short)f2bf(acc[fr][fc][0] + bias);
                o[1] = (short)f2bf(acc[fr][fc][1] + bias);
                o[2] = (short)f2bf(acc[fr][fc][2] + bias);
                o[3] = (short)f2bf(acc[fr][fc][3] + bias);
                *(s16x4*)&kTb[(size_t)cc * N_ + nb] = o;
            }
            #pragma unroll
            for (int fc = 4; fc < 8; fc++) {       // v half -> v[n][g]
                int cv = fc * 16 + lr - 64;
                float bias = bv[cv];
                #pragma unroll
                for (int r = 0; r < 4; r++)
                    v[(size_t)(nb + r) * G_ + cv] = acc[fr][fc][r] + bias;
            }
        }
    } else if (bid == 16) {
        // zero both summary accumulators (propagated_summary + relation_vector)
        #pragma unroll
        for (int j = 0; j < 8; j++) out[tid + j * 256] = 0.f;
        // ---- q projection via MFMA ----
        short* Hs = smem;           // [16][128] bf16
        short* Wqs = smem + 2048;   // [64][128] bf16
        f32x4 acc[4];
        #pragma unroll
        for (int fc = 0; fc < 4; fc++) acc[fc] = (f32x4){0.f, 0.f, 0.f, 0.f};
        for (int kt = 0; kt < 4; kt++) {
            __syncthreads();
            {   // stage h_t
                int row = tid >> 4, c16 = tid & 15;
                const float* src = h_t + (size_t)row * H_ + kt * 128 + c16 * 8;
                *(short8*)&Hs[(row * 16 + (c16 ^ (row & 7))) * 8] =
                    pack8(*(const f32x4*)src, *(const f32x4*)(src + 4));
            }
            #pragma unroll
            for (int j = 0; j < 4; j++) {          // stage Wq
                int c = tid + j * 256;
                int row = c >> 4, c16 = c & 15;
                const float* src = Wq + (size_t)row * H_ + kt * 128 + c16 * 8;
                *(short8*)&Wqs[(row * 16 + (c16 ^ (row & 7))) * 8] =
                    pack8(*(const f32x4*)src, *(const f32x4*)(src + 4));
            }
            __syncthreads();
            if (wave == 0) {
                #pragma unroll
                for (int ks = 0; ks < 4; ks++) {
                    short8 af = *(const short8*)&Hs[(lr * 16 + ((ks * 4 + kg) ^ (lr & 7))) * 8];
                    #pragma unroll
                    for (int fc = 0; fc < 4; fc++) {
                        int row = fc * 16 + lr;
                        short8 bf = *(const short8*)&Wqs[(row * 16 + ((ks * 4 + kg) ^ (row & 7))) * 8];
                        acc[fc] = __builtin_amdgcn_mfma_f32_16x16x32_bf16(af, bf, acc[fc], 0, 0, 0);
                    }
                }
            }
        }
        if (wave == 0) {
            #pragma unroll
            for (int fc = 0; fc < 4; fc++) {
                int gcol = fc * 16 + lr;
                float bias = bq[gcol];
                #pragma unroll
                for (int r = 0; r < 4; r++)
                    q[(kg * 4 + r) * G_ + gcol] = acc[fc][r] + bias;
            }
        }
    } else {
        // ---- rowsum + bf16 cast: one row per wave, no barriers ----
        const int n = (bid - 17) * 4 + wave;
        const f32x4* src = (const f32x4*)(base_adj + (size_t)n * N_);
        s16x4* dst = (s16x4*)(Abf + (size_t)n * N_);
        float s = 0.f;
        #pragma unroll
        for (int i = 0; i < 8; i++) {
            int m4 = l + i * 64;
            f32x4 x = src[m4];
            s += x[0] + x[1] + x[2] + x[3];
            s16x4 o;
            o[0] = (short)f2bf(x[0]); o[1] = (short)f2bf(x[1]);
            o[2] = (short)f2bf(x[2]); o[3] = (short)f2bf(x[3]);
            dst[m4] = o;
        }
        #pragma unroll
        for (int off = 32; off; off >>= 1) s += __shfl_xor(s, off, 64);
        if (l == 0) rowsum[n] = s;
    }
}

// ---------------- K2: softmax (redundant per chunk) + VpT slice + rel partial ----
__global__ __launch_bounds__(1024) void attn_kernel(const float* __restrict__ q,
                                                    const __hip_bfloat16* __restrict__ kTb,
                                                    const float* __restrict__ rowsum,
                                                    const float* __restrict__ v,
                                                    float* __restrict__ alpha,
                                                    float* __restrict__ dis,
                                                    __hip_bfloat16* __restrict__ VpT,
                                                    float* __restrict__ out) {
    __shared__ float qs[G_];
    __shared__ float red[16];
    __shared__ float bval;
    __shared__ float als[N_];
    __shared__ float dss[N_];
    __shared__ float vs[64 * 65];
    const int b = blockIdx.x, chunk = blockIdx.y, tid = threadIdx.x;
    if (tid < G_) qs[tid] = q[b * G_ + tid];
    __syncthreads();
    int n1 = tid, n2 = tid + 1024;
    float l1 = 0.f, l2 = 0.f;
    const unsigned short* kr = (const unsigned short*)kTb;
    #pragma unroll 8
    for (int g = 0; g < G_; g++) {
        float qq = qs[g];
        l1 = fmaf(qq, bf2f(kr[(size_t)g * N_ + n1]), l1);
        l2 = fmaf(qq, bf2f(kr[(size_t)g * N_ + n2]), l2);
    }
    l1 *= 0.125f; l2 *= 0.125f;
    float m = fmaxf(l1, l2);
    #pragma unroll
    for (int off = 32; off; off >>= 1) m = fmaxf(m, __shfl_xor(m, off, 64));
    if ((tid & 63) == 0) red[tid >> 6] = m;
    __syncthreads();
    if (tid < 16) {
        float x = red[tid];
        #pragma unroll
        for (int off = 8; off; off >>= 1) x = fmaxf(x, __shfl_xor(x, off, 16));
        if (tid == 0) bval = x;
    }
    __syncthreads();
    m = bval;
    __syncthreads();
    float e1 = expf(l1 - m), e2 = expf(l2 - m);
    float s = e1 + e2;
    #pragma unroll
    for (int off = 32; off; off >>= 1) s += __shfl_xor(s, off, 64);
    if ((tid & 63) == 0) red[tid >> 6] = s;
    __syncthreads();
    if (tid < 16) {
        float x = red[tid];
        #pragma unroll
        for (int off = 8; off; off >>= 1) x += __shfl_xor(x, off, 16);
        if (tid == 0) bval = x;
    }
    __syncthreads();
    float inv = 1.f / bval;
    float a1 = e1 * inv, a2 = e2 * inv;
    float d1 = rsqrtf(fmaf(a1, rowsum[n1], 1.f + 1e-8f));
    float d2 = rsqrtf(fmaf(a2, rowsum[n2], 1.f + 1e-8f));
    if (chunk == 0) {
        alpha[(size_t)b * N_ + n1] = a1;
        alpha[(size_t)b * N_ + n2] = a2;
        dis[(size_t)b * N_ + n1] = d1;
        dis[(size_t)b * N_ + n2] = d2;
    }
    als[n1] = a1; als[n2] = a2;
    dss[n1] = d1; dss[n2] = d2;

    // ---- phase 2: VpT slice [chunk*256, +256) + rel partial ----
    float relacc = 0.f;
    const int gg = tid >> 4, mq = (tid & 15) * 4;
    #pragma unroll
    for (int sub = 0; sub < 4; sub++) {
        const int m0 = chunk * 256 + sub * 64;
        __syncthreads();
        {
            int mm = tid >> 4, g4 = (tid & 15) << 2;
            f32x4 x = *(const f32x4*)&v[(size_t)(m0 + mm) * G_ + g4];
            vs[mm * 65 + g4 + 0] = x[0];
            vs[mm * 65 + g4 + 1] = x[1];
            vs[mm * 65 + g4 + 2] = x[2];
            vs[mm * 65 + g4 + 3] = x[3];
        }
        __syncthreads();
        s16x4 pk;
        #pragma unroll
        for (int j = 0; j < 4; j++) {
            int mm = mq + j;
            float vv = vs[mm * 65 + gg];
            pk[j] = (short)f2bf(dss[m0 + mm] * vv);
            relacc = fmaf(als[m0 + mm], vv, relacc);
        }
        *(s16x4*)&VpT[((size_t)b * G_ + gg) * N_ + m0 + mq] = pk;
    }
    __syncthreads();
    vs[tid] = relacc;
    __syncthreads();
    if (tid < G_) {
        float r = 0.f;
        #pragma unroll
        for (int i = 0; i < 16; i++) r += vs[tid * 16 + i];
        atomicAdd(&out[1024 + b * G_ + tid], r);   // relation_vector partial
    }
}

// ---------------- K3: bf16 GEMM (split-K across waves) + fused epilogue ---------
// BM=64, BN=64, BK=128. Wave w computes the FULL 64x64 output over k-slice w;
// partials reduced once through LDS. LDS tile bytes read exactly once.
#define BM 64
#define BN 64
#define BK 128
#define NKT (N_ / BK)   // 16 K-tiles
__global__ __launch_bounds__(256) void gemm_fused(const __hip_bfloat16* __restrict__ Abf,
                                                  const __hip_bfloat16* __restrict__ VpT,
                                                  const float* __restrict__ v,
                                                  const float* __restrict__ alpha,
                                                  const float* __restrict__ dis,
                                                  const float* __restrict__ Wo,
                                                  const float* __restrict__ bo,
                                                  const float* __restrict__ gamma,
                                                  const float* __restrict__ beta,
                                                  float* __restrict__ un,
                                                  float* __restrict__ outp) {
    // smem union: [0,16K)=A0 [16K,32K)=A1 [32K,48K)=B0 [48K,64K)=B1
    //             post-loop: [0,64K)=reduction buf; then [0,8K)=z_s, [32K,40K)=wo_s
    __shared__ __align__(16) char smem[65536 + 1536];
    float* ad_s = (float*)(smem + 65536);      // [2][64]: alpha, dis
    float* psum_w = (float*)(smem + 66048);    // [4][64]
    const int tid = threadIdx.x;
    const int wg = blockIdx.x;            // 0..511
    const int xcd = wg & 7, c = wg >> 3;  // c in 0..63
    const int n0 = (c >> 1) * BM;         // 32 row panels
    const int b = xcd * 2 + (c & 1);      // batch index
    const int c0 = b * BN;
    const int wave = tid >> 6, l = tid & 63;
    const int lr = l & 15, kg = l >> 4;

    if (tid < BM) {
        ad_s[tid] = alpha[(size_t)b * N_ + n0 + tid];
        ad_s[64 + tid] = dis[(size_t)b * N_ + n0 + tid];
    }

    f32x4 acc[4][4];
    #pragma unroll
    for (int m = 0; m < 4; m++)
        #pragma unroll
        for (int n = 0; n < 4; n++) acc[m][n] = (f32x4){0.f, 0.f, 0.f, 0.f};

    // staging: thread covers rows (tid>>4)+16j, 16B chunk c16 = tid&15,
    // source chunk pre-swizzled: (c16&8) | ((c16 ^ row) & 7); row&7 const across j.
    const int srow = tid >> 4;            // 0..15
    const int c16s = tid & 15;
    const int scol = ((c16s & 8) | ((c16s ^ srow) & 7)) << 3;  // element offset
    const __hip_bfloat16* ag = Abf + (size_t)(n0 + srow) * N_ + scol;
    const __hip_bfloat16* bg = VpT + (size_t)(c0 + srow) * N_ + scol;

    #define STAGE(bufidx, kpos)                                               \
        do {                                                                  \
            short* Ad = (short*)(smem + (bufidx) * 16384);                    \
            short* Bd = (short*)(smem + 32768 + (bufidx) * 16384);            \
            _Pragma("unroll")                                                 \
            for (int j = 0; j < 4; j++)                                       \
                gl_lds16(ag + (size_t)j * 16 * N_ + (kpos),                   \
                         &Ad[(wave * 4 + j * 16) * BK]);                      \
            _Pragma("unroll")                                                 \
            for (int j = 0; j < 4; j++)                                       \
                gl_lds16(bg + (size_t)j * 16 * N_ + (kpos),                   \
                         &Bd[(wave * 4 + j * 16) * BK]);                      \
        } while (0)

    STAGE(0, 0);
    __syncthreads();

    const int chunk = wave * 4 + kg;                    // this wave's k-chunk 0..15
    const int swc = ((chunk & 8) | ((chunk ^ lr) & 7)) * 8;
    int cur = 0;
    for (int t = 0; t < NKT; t++) {
        if (t + 1 < NKT) STAGE(cur ^ 1, (t + 1) * BK);
        const short* Ab = (const short*)(smem + cur * 16384);
        const short* Bb = (const short*)(smem + 32768 + cur * 16384);
        short8 av[4], bv2[4];
        #pragma unroll
        for (int m = 0; m < 4; m++)
            av[m] = *(const short8*)&Ab[(m * 16 + lr) * BK + swc];
        #pragma unroll
        for (int n = 0; n < 4; n++)
            bv2[n] = *(const short8*)&Bb[(n * 16 + lr) * BK + swc];
        #pragma unroll
        for (int m = 0; m < 4; m++)
            #pragma unroll
            for (int n = 0; n < 4; n++)
                acc[m][n] = __builtin_amdgcn_mfma_f32_16x16x32_bf16(av[m], bv2[n], acc[m][n], 0, 0, 0);
        __syncthreads();
        cur ^= 1;
    }
    #undef STAGE

    // ---------- cross-wave k-reduction through LDS ----------
    float* red = (float*)smem;   // 64 KB: [srcwave][frag m*4+n][lane] f32x4
    #pragma unroll
    for (int m = 0; m < 4; m++)
        #pragma unroll
        for (int n = 0; n < 4; n++)
            *(f32x4*)&red[((wave * 16 + m * 4 + n) * 64 + l) * 4] = acc[m][n];
    __syncthreads();
    f32x4 cfin[4];   // fragment (m=wave, n) final sums
    #pragma unroll
    for (int n = 0; n < 4; n++) {
        f32x4 s0 = *(const f32x4*)&red[((0 + wave * 4 + n) * 64 + l) * 4];
        f32x4 s1 = *(const f32x4*)&red[((16 + wave * 4 + n) * 64 + l) * 4];
        f32x4 s2 = *(const f32x4*)&red[((32 + wave * 4 + n) * 64 + l) * 4];
        f32x4 s3 = *(const f32x4*)&red[((48 + wave * 4 + n) * 64 + l) * 4];
        cfin[n] = (s0 + s1) + (s2 + s3);
    }
    __syncthreads();

    // ---------- fused epilogue ----------
    unsigned short* z_s = (unsigned short*)smem;          // z bf16 [64][64], swizzled
    uint32_t* wo_s = (uint32_t*)(smem + 32768);           // Wo bf16 packed [64][32dw], swizzled

    {   // stage Wo (f32 -> packed bf16, swizzle dword col by (g&7)<<2)
        int g = tid >> 2;
        int j0 = (tid & 3) * 16;
        #pragma unroll
        for (int jj = 0; jj < 8; jj++) {
            int g2 = j0 + jj * 2;
            uint32_t pk = (uint32_t)f2bf(Wo[g * G_ + g2]) |
                          ((uint32_t)f2bf(Wo[g * G_ + g2 + 1]) << 16);
            int dwc = ((g2 >> 1) ^ ((g & 7) << 2)) & 31;
            wo_s[g * 32 + dwc] = pk;
        }
    }
    // z' = di*(al*S + di*v), cast bf16, swizzle dword col by ((row>>2)&3)<<3
    #pragma unroll
    for (int nn = 0; nn < 4; nn++)
        #pragma unroll
        for (int r = 0; r < 4; r++) {
            int row = wave * 16 + kg * 4 + r;
            int g2 = nn * 16 + lr;
            float al = ad_s[row], di = ad_s[64 + row];
            float vv = v[(size_t)(n0 + row) * G_ + g2];
            float zp = di * fmaf(al, cfin[nn][r], di * vv);
            int dwc = ((g2 >> 1) ^ (((row >> 2) & 3) << 3)) & 31;
            z_s[(row * 32 + dwc) * 2 + (g2 & 1)] = f2bf(zp);
        }
    float bo_l[4], ga_l[4], be_l[4];
    #pragma unroll
    for (int ct = 0; ct < 4; ct++) {
        bo_l[ct] = bo[ct * 16 + lr];
        ga_l[ct] = gamma[ct * 16 + lr];
        be_l[ct] = beta[ct * 16 + lr];
    }
    __syncthreads();

    // 2nd MFMA: y = z @ Wo^T; wave handles rows [wave*16, +16)
    short8 aw[2], bw[4][2];
    #pragma unroll
    for (int kh = 0; kh < 2; kh++) {
        int arow = wave * 16 + lr;
        int dwc = ((kh * 16 + kg * 4) ^ (((arow >> 2) & 3) << 3)) & 31;
        aw[kh] = *(const short8*)&z_s[(arow * 32 + dwc) * 2];
    }
    #pragma unroll
    for (int ct = 0; ct < 4; ct++) {
        int col = ct * 16 + lr;
        #pragma unroll
        for (int kh = 0; kh < 2; kh++) {
            int dwc = ((kh * 16 + kg * 4) ^ ((col & 7) << 2)) & 31;
            bw[ct][kh] = *(const short8*)&((unsigned short*)wo_s)[(col * 32 + dwc) * 2];
        }
    }
    f32x4 acc2[4];
    #pragma unroll
    for (int ct = 0; ct < 4; ct++) acc2[ct] = (f32x4){0.f, 0.f, 0.f, 0.f};
    #pragma unroll
    for (int kh = 0; kh < 2; kh++)
        #pragma unroll
        for (int ct = 0; ct < 4; ct++)
            acc2[ct] = __builtin_amdgcn_mfma_f32_16x16x32_bf16(aw[kh], bw[ct][kh], acc2[ct], 0, 0, 0);

    // bias + ReLU + LayerNorm + store + psum
    float psum_l[4] = {0.f, 0.f, 0.f, 0.f};
    #pragma unroll
    for (int rr = 0; rr < 4; rr++) {
        int lrow = wave * 16 + kg * 4 + rr;
        float y[4], s = 0.f;
        #pragma unroll
        for (int ct = 0; ct < 4; ct++) {
            y[ct] = fmaxf(acc2[ct][rr] + bo_l[ct], 0.f);
            s += y[ct];
        }
        s += __shfl_xor(s, 1, 64); s += __shfl_xor(s, 2, 64);
        s += __shfl_xor(s, 4, 64); s += __shfl_xor(s, 8, 64);
        float mu = s * (1.f / 64.f);
        float s2 = 0.f;
        #pragma unroll
        for (int ct = 0; ct < 4; ct++) { float d = y[ct] - mu; s2 += d * d; }
        s2 += __shfl_xor(s2, 1, 64); s2 += __shfl_xor(s2, 2, 64);
        s2 += __shfl_xor(s2, 4, 64); s2 += __shfl_xor(s2, 8, 64);
        float rstd = rsqrtf(s2 * (1.f / 64.f) + 1e-5f);
        float al = ad_s[lrow];
        size_t ubase = ((size_t)b * N_ + n0 + lrow) * G_;
        #pragma unroll
        for (int ct = 0; ct < 4; ct++) {
            float outv = fmaf((y[ct] - mu) * rstd, ga_l[ct], be_l[ct]);
            un[ubase + ct * 16 + lr] = outv;
            psum_l[ct] = fmaf(al, outv, psum_l[ct]);
        }
    }
    #pragma unroll
    for (int ct = 0; ct < 4; ct++) {
        psum_l[ct] += __shfl_xor(psum_l[ct], 16, 64);
        psum_l[ct] += __shfl_xor(psum_l[ct], 32, 64);
    }
    if (kg == 0)
        #pragma unroll
        for (int ct = 0; ct < 4; ct++) psum_w[wave * 64 + ct * 16 + lr] = psum_l[ct];
    __syncthreads();
    if (tid < G_) {
        float p = psum_w[tid] + psum_w[64 + tid] + psum_w[128 + tid] + psum_w[192 + tid];
        atomicAdd(&outp[b * G_ + tid], p);     // propagated_summary
    }
}

extern "C" void kernel_launch(void* const* d_in, const int* in_sizes, int n_in,
                              void* d_out, int out_size, void* d_ws, size_t ws_size,
                              hipStream_t stream) {
    const float* h_t       = (const float*)d_in[0];
    const float* node_repr = (const float*)d_in[1];
    const float* base_adj  = (const float*)d_in[2];
    const float* Wq    = (const float*)d_in[3];
    const float* bq    = (const float*)d_in[4];
    const float* Wk    = (const float*)d_in[5];
    const float* bk    = (const float*)d_in[6];
    const float* Wv    = (const float*)d_in[7];
    const float* bv    = (const float*)d_in[8];
    const float* Wo    = (const float*)d_in[9];
    const float* bo    = (const float*)d_in[10];
    const float* gamma = (const float*)d_in[11];
    const float* beta  = (const float*)d_in[12];
    float* out = (float*)d_out;

    char* ws = (char*)d_ws;
    float* q      = (float*)(ws + OFF_Q);
    __hip_bfloat16* kTb = (__hip_bfloat16*)(ws + OFF_KT);
    float* v      = (float*)(ws + OFF_V);
    float* alpha  = (float*)(ws + OFF_ALPHA);
    float* dis    = (float*)(ws + OFF_DIS);
    float* rowsum = (float*)(ws + OFF_ROWSUM);
    __hip_bfloat16* Abf = (__hip_bfloat16*)(ws + OFF_ABF);
    __hip_bfloat16* VpT = (__hip_bfloat16*)(ws + OFF_VPT);

    float* un = out + 2048; // updated_nodes region

    prep_kernel<<<17 + 512, 256, 0, stream>>>(h_t, Wq, bq, node_repr, Wk, bk,
                                              Wv, bv, base_adj, q, kTb, v, Abf, rowsum, out);
    attn_kernel<<<dim3(B_, 8), 1024, 0, stream>>>(q, kTb, rowsum, v, alpha, dis, VpT, out);
    gemm_fused<<<(N_ / BM) * (B_ * G_ / BN), 256, 0, stream>>>(Abf, VpT, v, alpha, dis,
                                                               Wo, bo, gamma, beta, un, out);
}